// Round 1
// 87.719 us; speedup vs baseline: 1.0291x; 1.0291x over previous
//
#include <hip/hip_runtime.h>

// Problem constants (fixed by the reference setup)
#define B_ 128
#define N_ 65536
#define P_ 4096
#define T_ 32
#define D_ 2
#define K_ 4
#define S_ 8                       // slices per batch
#define PPB 512                    // pairs per block (P_/S_)

// sorted-descending top-4 insert chain (7 ops)
#define INS(v0, v1, v2, v3, val)                                  \
    {                                                             \
        float _x = fminf(v0, val); v0 = fmaxf(v0, val);           \
        float _y = fminf(v1, _x);  v1 = fmaxf(v1, _x);            \
        float _z = fminf(v2, _y);  v2 = fmaxf(v2, _y);            \
        v3 = fmaxf(v3, _z);                                       \
    }

// ---------------------------------------------------------------------------
// Fused kernel: each block owns (batch, slice) = 512 pairs.
//  1. gather b/d from fun (XCD-swizzled so one batch's blocks share an XCD)
//     with int2-vectorized index loads (thread t owns pairs 2t, 2t+1).
//  2. FILTER + partition: pairs with d <= b have tent <= 0 everywhere and can
//     never displace the 0-initialized accumulators (reference clamps them to
//     the same 0) -> drop them at the ballot-compaction step. ~50% of pairs
//     die here. Segments padded to x4 with sentinel pairs (4,-4).
//  3. scan: each wave reads FOUR same-dim pairs per iteration via one
//     ds_read_b128 per half (uniform addr -> broadcast). Lanes 0-31 evaluate
//     pairs j..j+1, lanes 32-63 pairs j+2..j+3, each half covering all 32 t.
//  4. shfl_xor(32) merge of halves, LDS merge of 4 waves, wave 0 writes the
//     per-slice partial top-4 for all 64 (dim,t) combos as one float4.
// ---------------------------------------------------------------------------
__global__ __launch_bounds__(256) void fused_scan(
        const float* __restrict__ fun,
        const int* __restrict__ bidx,
        const int* __restrict__ didx,
        const int* __restrict__ pdim,
        float* __restrict__ partial) {
    __shared__ __align__(16) float2 bdS[PPB + 8];
    __shared__ int cnt0S[8];
    __shared__ int cnt1S[8];
    __shared__ float mrg[4][64][4];

    int bid   = blockIdx.x;               // 0..1023
    int xcd   = bid & 7;
    int seq   = bid >> 3;                 // 0..127
    int batch = xcd * 16 + (seq & 15);    // all 8 slices of a batch on one XCD
    int slice = seq >> 4;                 // 0..7

    int tid  = threadIdx.x;
    int lane = tid & 63;
    int wave = tid >> 6;
    int base = batch * P_ + slice * PPB;

    // --- gather (int2 index loads; fun row mostly L2-resident per XCD) ---
    const float* f = fun + (size_t)batch * N_;
    int2 bi = ((const int2*)(bidx + base))[tid];   // pairs 2*tid, 2*tid+1
    int2 di = ((const int2*)(didx + base))[tid];
    int2 pd = ((const int2*)(pdim + base))[tid];
    float be = f[bi.x], de = f[di.x];
    float bo = f[bi.y], dd = f[di.y];

    // --- filter (d > b) + partition by dim via ballot compaction ---
    bool k0e = (pd.x == 0) && (de > be);
    bool k1e = (pd.x == 1) && (de > be);
    bool k0o = (pd.y == 0) && (dd > bo);
    bool k1o = (pd.y == 1) && (dd > bo);

    unsigned long long b0e = __ballot(k0e), b1e = __ballot(k1e);
    unsigned long long b0o = __ballot(k0o), b1o = __ballot(k1o);
    if (lane == 0) {
        cnt0S[wave * 2]     = __popcll(b0e);
        cnt0S[wave * 2 + 1] = __popcll(b0o);
        cnt1S[wave * 2]     = __popcll(b1e);
        cnt1S[wave * 2 + 1] = __popcll(b1o);
    }
    __syncthreads();

    int ce = wave * 2, co = ce + 1;
    int pre0e = 0, pre0o = 0, pre1e = 0, pre1o = 0, tot0 = 0, tot1 = 0;
    #pragma unroll
    for (int c = 0; c < 8; ++c) {
        int c0 = cnt0S[c], c1 = cnt1S[c];
        if (c < ce) { pre0e += c0; pre1e += c1; }
        if (c < co) { pre0o += c0; pre1o += c1; }
        tot0 += c0; tot1 += c1;
    }
    int A  = (tot0 + 3) & ~3;             // dim0 segment padded to x4
    int L1 = (tot1 + 3) & ~3;             // dim1 segment padded to x4

    unsigned long long lm = (1ull << lane) - 1ull;
    if (k0e) bdS[pre0e + __popcll(b0e & lm)]     = make_float2(be, de);
    if (k1e) bdS[A + pre1e + __popcll(b1e & lm)] = make_float2(be, de);
    if (k0o) bdS[pre0o + __popcll(b0o & lm)]     = make_float2(bo, dd);
    if (k1o) bdS[A + pre1o + __popcll(b1o & lm)] = make_float2(bo, dd);
    // sentinel padding (tent always negative): threads 0-2 pad seg0, 4-6 seg1
    if (tid < A - tot0)                    bdS[tot0 + tid]           = make_float2(4.f, -4.f);
    if (tid >= 4 && tid - 4 < L1 - tot1)   bdS[A + tot1 + (tid - 4)] = make_float2(4.f, -4.f);
    __syncthreads();

    // --- scan: four same-dim pairs per wave iteration, one b128 per half ---
    int half = lane >> 5;
    int t    = lane & 31;
    float tf = (float)(t + 1) * 0.03125f; // tseq[t], exact in fp32

    float a0 = 0.f, a1 = 0.f, a2 = 0.f, a3 = 0.f;  // dim0 partial top-4
    float c0 = 0.f, c1 = 0.f, c2 = 0.f, c3 = 0.f;  // dim1 partial top-4

    const float2* bd0 = bdS + 2 * half;
    #pragma unroll 2
    for (int j = wave * 4; j < A; j += 16) {
        float4 q = *(const float4*)(bd0 + j);
        float v0 = fminf(tf - q.x, q.y - tf);
        float v1 = fminf(tf - q.z, q.w - tf);
        INS(a0, a1, a2, a3, v0);
        INS(a0, a1, a2, a3, v1);
    }
    #pragma unroll 2
    for (int j = wave * 4; j < L1; j += 16) {
        float4 q = *(const float4*)(bd0 + A + j);
        float v0 = fminf(tf - q.x, q.y - tf);
        float v1 = fminf(tf - q.z, q.w - tf);
        INS(c0, c1, c2, c3, v0);
        INS(c0, c1, c2, c3, v1);
    }

    // --- even/odd half merge: partner lane l^32 holds same (t, dim) work ---
    float u0 = (half == 0) ? a0 : c0, w0 = (half == 0) ? c0 : a0;
    float u1 = (half == 0) ? a1 : c1, w1 = (half == 0) ? c1 : a1;
    float u2 = (half == 0) ? a2 : c2, w2 = (half == 0) ? c2 : a2;
    float u3 = (half == 0) ? a3 : c3, w3 = (half == 0) ? c3 : a3;
    float q;
    q = __shfl_xor(w0, 32); INS(u0, u1, u2, u3, q);
    q = __shfl_xor(w1, 32); INS(u0, u1, u2, u3, q);
    q = __shfl_xor(w2, 32); INS(u0, u1, u2, u3, q);
    q = __shfl_xor(w3, 32); INS(u0, u1, u2, u3, q);
    // lane l now holds top-4 for combo = l (dim = l>>5, t = l&31)

    mrg[wave][lane][0] = u0;
    mrg[wave][lane][1] = u1;
    mrg[wave][lane][2] = u2;
    mrg[wave][lane][3] = u3;
    __syncthreads();

    if (wave == 0) {
        float v0 = 0.f, v1 = 0.f, v2 = 0.f, v3 = 0.f;
        #pragma unroll
        for (int w = 0; w < 4; ++w) {
            #pragma unroll
            for (int k = 0; k < 4; ++k) {
                float val = mrg[w][lane][k];
                INS(v0, v1, v2, v3, val);
            }
        }
        ((float4*)partial)[((size_t)batch * S_ + slice) * 64 + lane] =
            make_float4(v0, v1, v2, v3);
    }
}

// ---------------------------------------------------------------------------
// Fold the 8 slice-partials per (batch, combo) into the final top-4.
// out index = batch*256 + combo*4 + k matches reference [B, D, T, K].
// ---------------------------------------------------------------------------
__global__ __launch_bounds__(256) void final_merge(
        const float* __restrict__ partial,
        float* __restrict__ out) {
    int tid   = blockIdx.x * 256 + threadIdx.x; // 0 .. B_*64-1
    int batch = tid >> 6;
    int combo = tid & 63;
    const float4* src = (const float4*)partial + (size_t)batch * S_ * 64 + combo;
    float v0 = 0.f, v1 = 0.f, v2 = 0.f, v3 = 0.f;
    #pragma unroll
    for (int s = 0; s < S_; ++s) {
        float4 p = src[(size_t)s * 64];
        INS(v0, v1, v2, v3, p.x);
        INS(v0, v1, v2, v3, p.y);
        INS(v0, v1, v2, v3, p.z);
        INS(v0, v1, v2, v3, p.w);
    }
    ((float4*)out)[tid] = make_float4(v0, v1, v2, v3);
}

extern "C" void kernel_launch(void* const* d_in, const int* in_sizes, int n_in,
                              void* d_out, int out_size, void* d_ws, size_t ws_size,
                              hipStream_t stream) {
    const float* fun  = (const float*)d_in[0]; // [B, N] f32
    const int*   bidx = (const int*)d_in[1];   // [B, P] i32
    const int*   didx = (const int*)d_in[2];   // [B, P] i32
    const int*   pdim = (const int*)d_in[3];   // [B, P] i32
    float* out = (float*)d_out;                // [B, D, T, K] f32

    float* partial = (float*)d_ws;             // B*S*64*4 f32 = 512 KB

    fused_scan<<<B_ * S_, 256, 0, stream>>>(fun, bidx, didx, pdim, partial);
    final_merge<<<(B_ * 64) / 256, 256, 0, stream>>>(partial, out);
}